// Round 1
// baseline (134.598 us; speedup 1.0000x reference)
//
#include <hip/hip_runtime.h>
#include <hip/hip_cooperative_groups.h>

namespace cg = cooperative_groups;

// SlotAttention: B=8, L=256, D=256, K=64
// Round-9: fuse proj+attn into ONE cooperative kernel (grid.sync):
//  - saves one kernel launch + full inter-kernel drain
//  - block's own Eq (4x64) and X rows (4x256) stay in LDS across the sync:
//    QK scratch shrinks to Ek-only (2048x64 = 512 KB), epilogue xcopy = LDS read
//  - proj now uses all 256 threads via d-split (two 128-long dots + LDS combine)
// Fallback: if cooperative launch is rejected, run the proven R8 two-kernel path.

#define Bn 8
#define Ln 256
#define Dn 256
#define Kn 64
#define ROWS (Bn*Ln)       // 2048
#define IPB 4              // query rows per block

// ==================== Fused cooperative kernel ====================
__global__ __launch_bounds__(256, 2) void fused_kernel(
    const float* __restrict__ X,     // (2048,256)
    const float* __restrict__ W1,    // (64,512)
    const float* __restrict__ W2,    // (64,)
    float* __restrict__ QKek,        // (2048,64) ws: Ek = e^{2*kj}
    float* __restrict__ out)         // (2048,512)
{
    __shared__ float Xs[IPB * Dn];        // 4 KB  (alive across grid.sync)
    __shared__ float eq_s[IPB * Kn];      // 1 KB  (alive across grid.sync)
    __shared__ float w2_s[Kn];            // 256 B
    __shared__ float pr[128 * 4];         // 2 KB  proj partial dots
    __shared__ float S[Ln * IPB];         // 4 KB
    __shared__ float4 red[4 * IPB * 64];  // 16 KB
    // total 27.3 KB -> 2 blocks/CU; 512 blocks co-resident on 256 CUs

    const int tid = threadIdx.x;
    const int blk = blockIdx.x;
    const int r0  = blk * IPB;            // this block's 4 global rows
    const int b   = blk >> 6;             // batch

    // ---------------- Part A: projection (d-split) ----------------
    ((float4*)Xs)[tid] = ((const float4*)(X + r0 * Dn))[tid];   // 4 rows
    if (tid < Kn) w2_s[tid] = W2[tid];
    __syncthreads();

    {
        const int c    = tid & 127;       // output col: c<64 Eq(k=c), c>=64 Ek(k=c-64)
        const int dh   = tid >> 7;        // d-half: 0 -> d[0:128), 1 -> d[128:256)
        const int k    = c & 63;
        const int half = c >> 6;
        const float4* Wrow = (const float4*)(W1 + k * (2 * Dn) + half * Dn + dh * (Dn / 2));
        const float4* x0p = (const float4*)(Xs + 0 * Dn + dh * (Dn / 2));
        const float4* x1p = (const float4*)(Xs + 1 * Dn + dh * (Dn / 2));
        const float4* x2p = (const float4*)(Xs + 2 * Dn + dh * (Dn / 2));
        const float4* x3p = (const float4*)(Xs + 3 * Dn + dh * (Dn / 2));
        float a0 = 0.f, a1 = 0.f, a2 = 0.f, a3 = 0.f;
        #pragma unroll 8
        for (int d4 = 0; d4 < 32; ++d4) {
            float4 w  = Wrow[d4];
            float4 x0 = x0p[d4], x1 = x1p[d4], x2 = x2p[d4], x3 = x3p[d4];  // LDS broadcast
            a0 = fmaf(w.x, x0.x, a0); a0 = fmaf(w.y, x0.y, a0);
            a0 = fmaf(w.z, x0.z, a0); a0 = fmaf(w.w, x0.w, a0);
            a1 = fmaf(w.x, x1.x, a1); a1 = fmaf(w.y, x1.y, a1);
            a1 = fmaf(w.z, x1.z, a1); a1 = fmaf(w.w, x1.w, a1);
            a2 = fmaf(w.x, x2.x, a2); a2 = fmaf(w.y, x2.y, a2);
            a2 = fmaf(w.z, x2.z, a2); a2 = fmaf(w.w, x2.w, a2);
            a3 = fmaf(w.x, x3.x, a3); a3 = fmaf(w.y, x3.y, a3);
            a3 = fmaf(w.z, x3.z, a3); a3 = fmaf(w.w, x3.w, a3);
        }
        if (dh) ((float4*)pr)[c] = make_float4(a0, a1, a2, a3);
        __syncthreads();
        if (!dh) {
            float4 p = ((const float4*)pr)[c];
            float e0 = __expf(2.0f * (a0 + p.x));
            float e1 = __expf(2.0f * (a1 + p.y));
            float e2 = __expf(2.0f * (a2 + p.z));
            float e3 = __expf(2.0f * (a3 + p.w));
            if (c < Kn) {                       // Eq stays in LDS — never goes global
                eq_s[0 * Kn + c] = e0; eq_s[1 * Kn + c] = e1;
                eq_s[2 * Kn + c] = e2; eq_s[3 * Kn + c] = e3;
            } else {                            // Ek -> global ws (coalesced 256B/row)
                const int kk = c - Kn;
                QKek[(r0 + 0) * Kn + kk] = e0; QKek[(r0 + 1) * Kn + kk] = e1;
                QKek[(r0 + 2) * Kn + kk] = e2; QKek[(r0 + 3) * Kn + kk] = e3;
            }
        }
    }

    cg::this_grid().sync();   // all Ek rows visible device-wide

    // ---------------- Part B: scores + softmax + context ----------------
    // thread owns key row j = tid: prefetch Ek row (64 floats) to registers
    float ekr[Kn];
    {
        const float4* kj4 = (const float4*)(QKek + (b * Ln + tid) * Kn);
        #pragma unroll
        for (int q = 0; q < 16; ++q) {
            float4 v = kj4[q];
            ekr[q * 4 + 0] = v.x; ekr[q * 4 + 1] = v.y;
            ekr[q * 4 + 2] = v.z; ekr[q * 4 + 3] = v.w;
        }
    }

    // Phase 1: T_i = sum_k w_k * rcp(Eq_ik*Ek_k + 1); score used = -2T
    float s[IPB] = {0, 0, 0, 0};
    {
        const float4* w4  = (const float4*)w2_s;
        const float4* q4a = (const float4*)(eq_s);
        const float4* q4b = (const float4*)(eq_s + Kn);
        const float4* q4c = (const float4*)(eq_s + 2 * Kn);
        const float4* q4d = (const float4*)(eq_s + 3 * Kn);
        #pragma unroll
        for (int k4 = 0; k4 < 16; ++k4) {
            float4 w  = w4[k4];
            float4 q0 = q4a[k4], q1 = q4b[k4], q2 = q4c[k4], q3 = q4d[k4];
            #pragma unroll
            for (int c = 0; c < 4; ++c) {
                float ek = ekr[k4 * 4 + c];
                float wk = (c == 0) ? w.x : (c == 1) ? w.y : (c == 2) ? w.z : w.w;
                float e0 = (c == 0) ? q0.x : (c == 1) ? q0.y : (c == 2) ? q0.z : q0.w;
                float e1 = (c == 0) ? q1.x : (c == 1) ? q1.y : (c == 2) ? q1.z : q1.w;
                float e2 = (c == 0) ? q2.x : (c == 1) ? q2.y : (c == 2) ? q2.z : q2.w;
                float e3 = (c == 0) ? q3.x : (c == 1) ? q3.y : (c == 2) ? q3.z : q3.w;
                s[0] = fmaf(wk, __builtin_amdgcn_rcpf(fmaf(e0, ek, 1.0f)), s[0]);
                s[1] = fmaf(wk, __builtin_amdgcn_rcpf(fmaf(e1, ek, 1.0f)), s[1]);
                s[2] = fmaf(wk, __builtin_amdgcn_rcpf(fmaf(e2, ek, 1.0f)), s[2]);
                s[3] = fmaf(wk, __builtin_amdgcn_rcpf(fmaf(e3, ek, 1.0f)), s[3]);
            }
        }
    }
    ((float4*)S)[tid] = make_float4(s[0], s[1], s[2], s[3]);   // S[j][i] = T
    __syncthreads();

    // Phase 2: softmax over j of (-2T); wave wv owns row i=wv.
    {
        const int wv = tid >> 6, lane = tid & 63;
        float e0 = __expf(-2.0f * S[(lane      ) * IPB + wv]);
        float e1 = __expf(-2.0f * S[(lane +  64) * IPB + wv]);
        float e2 = __expf(-2.0f * S[(lane + 128) * IPB + wv]);
        float e3 = __expf(-2.0f * S[(lane + 192) * IPB + wv]);
        float sum = (e0 + e1) + (e2 + e3);
        #pragma unroll
        for (int off = 32; off > 0; off >>= 1)
            sum += __shfl_xor(sum, off);
        float inv = 1.0f / sum;
        S[(lane      ) * IPB + wv] = e0 * inv;
        S[(lane +  64) * IPB + wv] = e1 * inv;
        S[(lane + 128) * IPB + wv] = e2 * inv;
        S[(lane + 192) * IPB + wv] = e3 * inv;
    }
    __syncthreads();

    // Phase 3: context, j split across waves; float4 X loads, LDS cross-wave reduce
    {
        const int wv = tid >> 6, lane = tid & 63;
        float4 acc0 = {0,0,0,0}, acc1 = {0,0,0,0}, acc2 = {0,0,0,0}, acc3 = {0,0,0,0};
        const float4* Xb4 = (const float4*)(X + b * Ln * Dn);
        const float4* S4  = (const float4*)S;
        const int jbase = wv * 64;
        #pragma unroll 8
        for (int jj = 0; jj < 64; ++jj) {
            int j = jbase + jj;
            float4 at = S4[j];                 // uniform broadcast b128
            float4 x  = Xb4[j * 64 + lane];    // coalesced 1 KB/wave
            acc0.x = fmaf(at.x, x.x, acc0.x); acc0.y = fmaf(at.x, x.y, acc0.y);
            acc0.z = fmaf(at.x, x.z, acc0.z); acc0.w = fmaf(at.x, x.w, acc0.w);
            acc1.x = fmaf(at.y, x.x, acc1.x); acc1.y = fmaf(at.y, x.y, acc1.y);
            acc1.z = fmaf(at.y, x.z, acc1.z); acc1.w = fmaf(at.y, x.w, acc1.w);
            acc2.x = fmaf(at.z, x.x, acc2.x); acc2.y = fmaf(at.z, x.y, acc2.y);
            acc2.z = fmaf(at.z, x.z, acc2.z); acc2.w = fmaf(at.z, x.w, acc2.w);
            acc3.x = fmaf(at.w, x.x, acc3.x); acc3.y = fmaf(at.w, x.y, acc3.y);
            acc3.z = fmaf(at.w, x.z, acc3.z); acc3.w = fmaf(at.w, x.w, acc3.w);
        }
        red[(wv * IPB + 0) * 64 + lane] = acc0;
        red[(wv * IPB + 1) * 64 + lane] = acc1;
        red[(wv * IPB + 2) * 64 + lane] = acc2;
        red[(wv * IPB + 3) * 64 + lane] = acc3;
    }
    __syncthreads();

    // Cross-wave reduce + b128 stores; inputs half comes from Xs (LDS), not global
    {
        const int i = tid >> 6, q = tid & 63;
        float4 p0 = red[(0 * IPB + i) * 64 + q];
        float4 p1 = red[(1 * IPB + i) * 64 + q];
        float4 p2 = red[(2 * IPB + i) * 64 + q];
        float4 p3 = red[(3 * IPB + i) * 64 + q];
        float4 c;
        c.x = (p0.x + p1.x) + (p2.x + p3.x);
        c.y = (p0.y + p1.y) + (p2.y + p3.y);
        c.z = (p0.z + p1.z) + (p2.z + p3.z);
        c.w = (p0.w + p1.w) + (p2.w + p3.w);
        const int row = r0 + i;
        float4 xcopy = ((const float4*)(Xs + i * Dn))[q];
        ((float4*)(out + row * 2 * Dn))[q]      = xcopy;  // inputs half
        ((float4*)(out + row * 2 * Dn + Dn))[q] = c;      // context half
    }
}

// ==================== Fallback: proven R8 two-kernel path ====================
__global__ __launch_bounds__(128) void proj_kernel(
    const float* __restrict__ X, const float* __restrict__ W1, float* __restrict__ QK)
{
    __shared__ float Xs[4 * 256];
    const int tid = threadIdx.x;
    const int r0 = blockIdx.x * 4;
    const float4* Xg4 = (const float4*)(X + r0 * Dn);
    float4* Xs4 = (float4*)Xs;
    #pragma unroll
    for (int idx = tid; idx < 256; idx += 128) Xs4[idx] = Xg4[idx];
    __syncthreads();
    const int k = tid & 63, half = tid >> 6;
    const float4* Wrow = (const float4*)(W1 + k * (2 * Dn) + half * Dn);
    float acc[4] = {0, 0, 0, 0};
    #pragma unroll 8
    for (int d4 = 0; d4 < 64; ++d4) {
        float4 w = Wrow[d4];
        #pragma unroll
        for (int r = 0; r < 4; ++r) {
            float4 x = ((const float4*)(Xs + r * Dn))[d4];
            float a = acc[r];
            a = fmaf(w.x, x.x, a); a = fmaf(w.y, x.y, a);
            a = fmaf(w.z, x.z, a); a = fmaf(w.w, x.w, a);
            acc[r] = a;
        }
    }
    #pragma unroll
    for (int r = 0; r < 4; ++r)
        QK[(r0 + r) * 128 + tid] = __expf(2.0f * acc[r]);
}

__global__ __launch_bounds__(256) void attn_kernel(
    const float* __restrict__ X, const float* __restrict__ QK,
    const float* __restrict__ W2, float* __restrict__ out)
{
    __shared__ float eq_s[IPB * Kn];
    __shared__ float w2_s[Kn];
    __shared__ float S[Ln * IPB];
    __shared__ float4 red[4 * IPB * 64];
    const int tid = threadIdx.x;
    const int b  = blockIdx.x / (Ln / IPB);
    const int i0 = (blockIdx.x % (Ln / IPB)) * IPB;
    if (tid < Kn) w2_s[tid] = W2[tid];
    {
        int ii = tid >> 6, kk = tid & 63;
        eq_s[ii * Kn + kk] = QK[(b * Ln + i0 + ii) * 128 + kk];
    }
    float ekr[Kn];
    const float4* kj4 = (const float4*)(QK + (b * Ln + tid) * 128 + 64);
    #pragma unroll
    for (int q = 0; q < 16; ++q) {
        float4 v = kj4[q];
        ekr[q * 4 + 0] = v.x; ekr[q * 4 + 1] = v.y;
        ekr[q * 4 + 2] = v.z; ekr[q * 4 + 3] = v.w;
    }
    __syncthreads();
    float s[IPB] = {0, 0, 0, 0};
    const float4* w4  = (const float4*)w2_s;
    const float4* q4a = (const float4*)(eq_s);
    const float4* q4b = (const float4*)(eq_s + Kn);
    const float4* q4c = (const float4*)(eq_s + 2 * Kn);
    const float4* q4d = (const float4*)(eq_s + 3 * Kn);
    #pragma unroll
    for (int k4 = 0; k4 < 16; ++k4) {
        float4 w  = w4[k4];
        float4 q0 = q4a[k4], q1 = q4b[k4], q2 = q4c[k4], q3 = q4d[k4];
        #pragma unroll
        for (int c = 0; c < 4; ++c) {
            float ek = ekr[k4 * 4 + c];
            float wk = (c == 0) ? w.x : (c == 1) ? w.y : (c == 2) ? w.z : w.w;
            float e0 = (c == 0) ? q0.x : (c == 1) ? q0.y : (c == 2) ? q0.z : q0.w;
            float e1 = (c == 0) ? q1.x : (c == 1) ? q1.y : (c == 2) ? q1.z : q1.w;
            float e2 = (c == 0) ? q2.x : (c == 1) ? q2.y : (c == 2) ? q2.z : q2.w;
            float e3 = (c == 0) ? q3.x : (c == 1) ? q3.y : (c == 2) ? q3.z : q3.w;
            s[0] = fmaf(wk, __builtin_amdgcn_rcpf(fmaf(e0, ek, 1.0f)), s[0]);
            s[1] = fmaf(wk, __builtin_amdgcn_rcpf(fmaf(e1, ek, 1.0f)), s[1]);
            s[2] = fmaf(wk, __builtin_amdgcn_rcpf(fmaf(e2, ek, 1.0f)), s[2]);
            s[3] = fmaf(wk, __builtin_amdgcn_rcpf(fmaf(e3, ek, 1.0f)), s[3]);
        }
    }
    ((float4*)S)[tid] = make_float4(s[0], s[1], s[2], s[3]);
    __syncthreads();
    {
        const int wv = tid >> 6, lane = tid & 63;
        float e0 = __expf(-2.0f * S[(lane      ) * IPB + wv]);
        float e1 = __expf(-2.0f * S[(lane +  64) * IPB + wv]);
        float e2 = __expf(-2.0f * S[(lane + 128) * IPB + wv]);
        float e3 = __expf(-2.0f * S[(lane + 192) * IPB + wv]);
        float sum = (e0 + e1) + (e2 + e3);
        #pragma unroll
        for (int off = 32; off > 0; off >>= 1)
            sum += __shfl_xor(sum, off);
        float inv = 1.0f / sum;
        S[(lane      ) * IPB + wv] = e0 * inv;
        S[(lane +  64) * IPB + wv] = e1 * inv;
        S[(lane + 128) * IPB + wv] = e2 * inv;
        S[(lane + 192) * IPB + wv] = e3 * inv;
    }
    __syncthreads();
    {
        const int wv = tid >> 6, lane = tid & 63;
        float4 acc0 = {0,0,0,0}, acc1 = {0,0,0,0}, acc2 = {0,0,0,0}, acc3 = {0,0,0,0};
        const float4* Xb4 = (const float4*)(X + b * Ln * Dn);
        const float4* S4  = (const float4*)S;
        const int jbase = wv * 64;
        #pragma unroll 8
        for (int jj = 0; jj < 64; ++jj) {
            int j = jbase + jj;
            float4 at = S4[j];
            float4 x  = Xb4[j * 64 + lane];
            acc0.x = fmaf(at.x, x.x, acc0.x); acc0.y = fmaf(at.x, x.y, acc0.y);
            acc0.z = fmaf(at.x, x.z, acc0.z); acc0.w = fmaf(at.x, x.w, acc0.w);
            acc1.x = fmaf(at.y, x.x, acc1.x); acc1.y = fmaf(at.y, x.y, acc1.y);
            acc1.z = fmaf(at.y, x.z, acc1.z); acc1.w = fmaf(at.y, x.w, acc1.w);
            acc2.x = fmaf(at.z, x.x, acc2.x); acc2.y = fmaf(at.z, x.y, acc2.y);
            acc2.z = fmaf(at.z, x.z, acc2.z); acc2.w = fmaf(at.z, x.w, acc2.w);
            acc3.x = fmaf(at.w, x.x, acc3.x); acc3.y = fmaf(at.w, x.y, acc3.y);
            acc3.z = fmaf(at.w, x.z, acc3.z); acc3.w = fmaf(at.w, x.w, acc3.w);
        }
        red[(wv * IPB + 0) * 64 + lane] = acc0;
        red[(wv * IPB + 1) * 64 + lane] = acc1;
        red[(wv * IPB + 2) * 64 + lane] = acc2;
        red[(wv * IPB + 3) * 64 + lane] = acc3;
    }
    __syncthreads();
    {
        const int i = tid >> 6, q = tid & 63;
        float4 p0 = red[(0 * IPB + i) * 64 + q];
        float4 p1 = red[(1 * IPB + i) * 64 + q];
        float4 p2 = red[(2 * IPB + i) * 64 + q];
        float4 p3 = red[(3 * IPB + i) * 64 + q];
        float4 c;
        c.x = (p0.x + p1.x) + (p2.x + p3.x);
        c.y = (p0.y + p1.y) + (p2.y + p3.y);
        c.z = (p0.z + p1.z) + (p2.z + p3.z);
        c.w = (p0.w + p1.w) + (p2.w + p3.w);
        const int row = b * Ln + i0 + i;
        float4 xcopy = ((const float4*)(X + row * Dn))[q];
        ((float4*)(out + row * 2 * Dn))[q]      = xcopy;
        ((float4*)(out + row * 2 * Dn + Dn))[q] = c;
    }
}

extern "C" void kernel_launch(void* const* d_in, const int* in_sizes, int n_in,
                              void* d_out, int out_size, void* d_ws, size_t ws_size,
                              hipStream_t stream) {
    const float* X  = (const float*)d_in[0];   // (8,256,256)
    const float* W1 = (const float*)d_in[1];   // (64,512)
    const float* W2 = (const float*)d_in[2];   // (1,64)
    float* out = (float*)d_out;                // (8,256,512)
    float* ws  = (float*)d_ws;                 // >= 512 KB scratch (Ek)

    void* args[] = {(void*)&X, (void*)&W1, (void*)&W2, (void*)&ws, (void*)&out};
    hipError_t err = hipLaunchCooperativeKernel((const void*)fused_kernel,
                                                dim3(ROWS / IPB), dim3(256),
                                                args, 0, stream);
    if (err != hipSuccess) {
        // Cooperative launch rejected (capture or residency): proven R8 path.
        proj_kernel<<<ROWS / 4, 128, 0, stream>>>(X, W1, ws);
        attn_kernel<<<ROWS / IPB, 256, 0, stream>>>(X, ws, W2, out);
    }
}

// Round 2
// 84.957 us; speedup vs baseline: 1.5843x; 1.5843x over previous
//
#include <hip/hip_runtime.h>

// SlotAttention: B=8, L=256, D=256, K=64
// Round-10: back to the proven two-kernel structure (cooperative fusion regressed:
// 134us, VALUBusy 10%, occupancy 21% -> latency-bound, plus ~65us capture overhead).
// Counter-driven changes vs R8 (79.7us):
//  - attn: IPB 4->2  => grid 1024 blocks, 4 blocks/CU, 4 waves/SIMD (was 2).
//          LDS 21.3KB -> 10.8KB. Same total work, 2x latency hiding.
//  - proj: 256 threads with d-split (verified in fused round) => 2 waves/SIMD (was 1).
// Math identical to R8: tanh(q+k) = 1 - 2/(Eq*Ek+1); score = -2T (shift-invariant
// softmax, no max-subtract needed since |2T| <= ~13).

#define Bn 8
#define Ln 256
#define Dn 256
#define Kn 64
#define ROWS (Bn*Ln)       // 2048
#define IPB 2              // query rows per attn block (R10: was 4)

// ---------------- Kernel A: projection -> exp form (256 thr, d-split) ----------------
// QK[row][c]: c<64 -> Eq = e^{2*qi[k=c]}, c>=64 -> Ek = e^{2*kj[k=c-64]}
__global__ __launch_bounds__(256) void proj_kernel(
    const float* __restrict__ X,    // (2048,256)
    const float* __restrict__ W1,   // (64,512)
    float* __restrict__ QK)         // (2048,128)
{
    __shared__ float Xs[4 * Dn];    // 4 rows, 4 KB
    __shared__ float pr[128 * 4];   // 2 KB partial dots (d-half 1)
    const int tid = threadIdx.x;
    const int r0 = blockIdx.x * 4;

    ((float4*)Xs)[tid] = ((const float4*)(X + r0 * Dn))[tid];   // 4 rows coalesced
    __syncthreads();

    const int c    = tid & 127;     // output col: c<64 Eq(k=c), c>=64 Ek(k=c-64)
    const int dh   = tid >> 7;      // d-half: 0 -> d[0:128), 1 -> d[128:256)
    const int k    = c & 63;
    const int half = c >> 6;
    const float4* Wrow = (const float4*)(W1 + k * (2 * Dn) + half * Dn + dh * (Dn / 2));
    const float4* x0p = (const float4*)(Xs + 0 * Dn + dh * (Dn / 2));
    const float4* x1p = (const float4*)(Xs + 1 * Dn + dh * (Dn / 2));
    const float4* x2p = (const float4*)(Xs + 2 * Dn + dh * (Dn / 2));
    const float4* x3p = (const float4*)(Xs + 3 * Dn + dh * (Dn / 2));
    float a0 = 0.f, a1 = 0.f, a2 = 0.f, a3 = 0.f;
    #pragma unroll 8
    for (int d4 = 0; d4 < 32; ++d4) {
        float4 w  = Wrow[d4];
        float4 x0 = x0p[d4], x1 = x1p[d4], x2 = x2p[d4], x3 = x3p[d4];  // LDS broadcast
        a0 = fmaf(w.x, x0.x, a0); a0 = fmaf(w.y, x0.y, a0);
        a0 = fmaf(w.z, x0.z, a0); a0 = fmaf(w.w, x0.w, a0);
        a1 = fmaf(w.x, x1.x, a1); a1 = fmaf(w.y, x1.y, a1);
        a1 = fmaf(w.z, x1.z, a1); a1 = fmaf(w.w, x1.w, a1);
        a2 = fmaf(w.x, x2.x, a2); a2 = fmaf(w.y, x2.y, a2);
        a2 = fmaf(w.z, x2.z, a2); a2 = fmaf(w.w, x2.w, a2);
        a3 = fmaf(w.x, x3.x, a3); a3 = fmaf(w.y, x3.y, a3);
        a3 = fmaf(w.z, x3.z, a3); a3 = fmaf(w.w, x3.w, a3);
    }
    if (dh) ((float4*)pr)[c] = make_float4(a0, a1, a2, a3);
    __syncthreads();
    if (!dh) {
        float4 p = ((const float4*)pr)[c];
        QK[(r0 + 0) * 128 + c] = __expf(2.0f * (a0 + p.x));
        QK[(r0 + 1) * 128 + c] = __expf(2.0f * (a1 + p.y));
        QK[(r0 + 2) * 128 + c] = __expf(2.0f * (a2 + p.z));
        QK[(r0 + 3) * 128 + c] = __expf(2.0f * (a3 + p.w));
    }
}

// ---------------- Kernel B: scores + softmax + context (IPB=2) ----------------
// grid = ROWS/IPB = 1024 blocks, 256 threads. Block handles rows i0..i0+1 of batch b.
__global__ __launch_bounds__(256) void attn_kernel(
    const float* __restrict__ X,    // (2048,256)
    const float* __restrict__ QK,   // (2048,128) exp'd
    const float* __restrict__ W2,   // (64,)
    float* __restrict__ out)        // (2048,512)
{
    __shared__ float eq_s[IPB * Kn];        // [i][k], 512 B
    __shared__ float w2_s[Kn];              // 256 B
    __shared__ float S[Ln * IPB];           // [j][i], 2 KB
    __shared__ float4 red[4 * IPB * 64];    // [wv][i][dquad], 8 KB

    const int tid = threadIdx.x;
    const int b  = blockIdx.x >> 7;             // 128 blocks per batch
    const int i0 = (blockIdx.x & 127) * IPB;

    if (tid < Kn) w2_s[tid] = W2[tid];
    if (tid < IPB * Kn) {   // Eq for the 2 query rows
        int ii = tid >> 6, kk = tid & 63;
        eq_s[ii * Kn + kk] = QK[(b * Ln + i0 + ii) * 128 + kk];
    }

    // thread owns key row j = tid: prefetch Ek row (64 floats) to registers
    float ekr[Kn];
    const float4* kj4 = (const float4*)(QK + (b * Ln + tid) * 128 + 64);
    #pragma unroll
    for (int q = 0; q < 16; ++q) {
        float4 v = kj4[q];
        ekr[q * 4 + 0] = v.x; ekr[q * 4 + 1] = v.y;
        ekr[q * 4 + 2] = v.z; ekr[q * 4 + 3] = v.w;
    }
    __syncthreads();

    // Phase 1: T_i = sum_k w_k * rcp(Eq_ik*Ek_k + 1); score used = -2T
    float s0 = 0.f, s1 = 0.f;
    {
        const float4* w4  = (const float4*)w2_s;
        const float4* q4a = (const float4*)(eq_s);
        const float4* q4b = (const float4*)(eq_s + Kn);
        #pragma unroll
        for (int k4 = 0; k4 < 16; ++k4) {
            float4 w  = w4[k4];
            float4 q0 = q4a[k4], q1 = q4b[k4];
            #pragma unroll
            for (int c = 0; c < 4; ++c) {
                float ek = ekr[k4 * 4 + c];
                float wk = (c == 0) ? w.x : (c == 1) ? w.y : (c == 2) ? w.z : w.w;
                float e0 = (c == 0) ? q0.x : (c == 1) ? q0.y : (c == 2) ? q0.z : q0.w;
                float e1 = (c == 0) ? q1.x : (c == 1) ? q1.y : (c == 2) ? q1.z : q1.w;
                s0 = fmaf(wk, __builtin_amdgcn_rcpf(fmaf(e0, ek, 1.0f)), s0);
                s1 = fmaf(wk, __builtin_amdgcn_rcpf(fmaf(e1, ek, 1.0f)), s1);
            }
        }
    }
    ((float2*)S)[tid] = make_float2(s0, s1);    // S[j][i] = T
    __syncthreads();

    // Phase 2: softmax over j of (-2T); wave wv (<2) owns row i=wv.
    {
        const int wv = tid >> 6, lane = tid & 63;
        if (wv < IPB) {
            float e0 = __expf(-2.0f * S[(lane      ) * IPB + wv]);
            float e1 = __expf(-2.0f * S[(lane +  64) * IPB + wv]);
            float e2 = __expf(-2.0f * S[(lane + 128) * IPB + wv]);
            float e3 = __expf(-2.0f * S[(lane + 192) * IPB + wv]);
            float sum = (e0 + e1) + (e2 + e3);
            #pragma unroll
            for (int off = 32; off > 0; off >>= 1)
                sum += __shfl_xor(sum, off);
            float inv = 1.0f / sum;
            S[(lane      ) * IPB + wv] = e0 * inv;
            S[(lane +  64) * IPB + wv] = e1 * inv;
            S[(lane + 128) * IPB + wv] = e2 * inv;
            S[(lane + 192) * IPB + wv] = e3 * inv;
        }
    }
    __syncthreads();

    // Phase 3: context, j split across 4 waves; float4 X loads, LDS cross-wave reduce
    {
        const int wv = tid >> 6, lane = tid & 63;
        float4 acc0 = {0,0,0,0}, acc1 = {0,0,0,0};
        const float4* Xb4 = (const float4*)(X + b * Ln * Dn);
        const float2* S2  = (const float2*)S;
        const int jbase = wv * 64;
        #pragma unroll 8
        for (int jj = 0; jj < 64; ++jj) {
            int j = jbase + jj;
            float2 at = S2[j];                 // uniform broadcast
            float4 x  = Xb4[j * 64 + lane];    // coalesced 1 KB/wave
            acc0.x = fmaf(at.x, x.x, acc0.x); acc0.y = fmaf(at.x, x.y, acc0.y);
            acc0.z = fmaf(at.x, x.z, acc0.z); acc0.w = fmaf(at.x, x.w, acc0.w);
            acc1.x = fmaf(at.y, x.x, acc1.x); acc1.y = fmaf(at.y, x.y, acc1.y);
            acc1.z = fmaf(at.y, x.z, acc1.z); acc1.w = fmaf(at.y, x.w, acc1.w);
        }
        red[(wv * IPB + 0) * 64 + lane] = acc0;
        red[(wv * IPB + 1) * 64 + lane] = acc1;
    }
    __syncthreads();

    // Cross-wave reduce + b128 stores.
    // tid<128: reduce + context store; tid>=128: inputs copy (parallel halves).
    {
        const int i = (tid & 127) >> 6, q = tid & 63;
        const int row = b * Ln + i0 + i;
        if (tid < 128) {
            float4 p0 = red[(0 * IPB + i) * 64 + q];
            float4 p1 = red[(1 * IPB + i) * 64 + q];
            float4 p2 = red[(2 * IPB + i) * 64 + q];
            float4 p3 = red[(3 * IPB + i) * 64 + q];
            float4 c;
            c.x = (p0.x + p1.x) + (p2.x + p3.x);
            c.y = (p0.y + p1.y) + (p2.y + p3.y);
            c.z = (p0.z + p1.z) + (p2.z + p3.z);
            c.w = (p0.w + p1.w) + (p2.w + p3.w);
            ((float4*)(out + row * 2 * Dn + Dn))[q] = c;      // context half
        } else {
            float4 xcopy = ((const float4*)(X + row * Dn))[q];
            ((float4*)(out + row * 2 * Dn))[q] = xcopy;       // inputs half
        }
    }
}

extern "C" void kernel_launch(void* const* d_in, const int* in_sizes, int n_in,
                              void* d_out, int out_size, void* d_ws, size_t ws_size,
                              hipStream_t stream) {
    const float* X  = (const float*)d_in[0];   // (8,256,256)
    const float* W1 = (const float*)d_in[1];   // (64,512)
    const float* W2 = (const float*)d_in[2];   // (1,64)
    float* out = (float*)d_out;                // (8,256,512)
    float* QK  = (float*)d_ws;                 // (2048,128) = 1 MB scratch

    proj_kernel<<<ROWS / 4, 256, 0, stream>>>(X, W1, QK);
    attn_kernel<<<ROWS / IPB, 256, 0, stream>>>(X, QK, W2, out);
}

// Round 3
// 79.016 us; speedup vs baseline: 1.7034x; 1.0752x over previous
//
#include <hip/hip_runtime.h>

// SlotAttention: B=8, L=256, D=256, K=64
// Round-11: R2 (IPB=2) regressed because per-block FIXED costs (X[b] stream, Ek
// prefetch) scale with block count. Root cause of slowness (from R1 fused counters:
// VALUBusy 10%, Occ 21%) is latency-bound execution at 2 blocks/CU -- the grid
// (512 blocks) caps occupancy, not resources.
// Fix: IPB=4 (grid 512, best amortization) but 512 THREADS/block (8 waves):
//   - phase 1: k-split (each thread owns 32 of 64 k's; partials combined via LDS,
//     transposed layout -> conflict-free)
//   - phase 3: j-split 8 ways (32 j per wave)
//   - waves 4-7 do the inputs->out copy DURING phase-2 softmax (were idle)
// Work per block unchanged; waves/CU: 8 -> 16 (2->4 per SIMD).
// Math identical: tanh(q+k) = 1 - 2/(Eq*Ek+1); score = -2T; shift-invariant softmax.

#define Bn 8
#define Ln 256
#define Dn 256
#define Kn 64
#define ROWS (Bn*Ln)       // 2048
#define IPB 4              // query rows per attn block

// ---------------- Kernel A: projection -> exp form (256 thr, d-split) ----------------
// QK[row][c]: c<64 -> Eq = e^{2*qi[k=c]}, c>=64 -> Ek = e^{2*kj[k=c-64]}
__global__ __launch_bounds__(256) void proj_kernel(
    const float* __restrict__ X,    // (2048,256)
    const float* __restrict__ W1,   // (64,512)
    float* __restrict__ QK)         // (2048,128)
{
    __shared__ float Xs[4 * Dn];    // 4 rows, 4 KB
    __shared__ float pr[128 * 4];   // 2 KB partial dots (d-half 1)
    const int tid = threadIdx.x;
    const int r0 = blockIdx.x * 4;

    ((float4*)Xs)[tid] = ((const float4*)(X + r0 * Dn))[tid];   // 4 rows coalesced
    __syncthreads();

    const int c    = tid & 127;     // output col: c<64 Eq(k=c), c>=64 Ek(k=c-64)
    const int dh   = tid >> 7;      // d-half: 0 -> d[0:128), 1 -> d[128:256)
    const int k    = c & 63;
    const int half = c >> 6;
    const float4* Wrow = (const float4*)(W1 + k * (2 * Dn) + half * Dn + dh * (Dn / 2));
    const float4* x0p = (const float4*)(Xs + 0 * Dn + dh * (Dn / 2));
    const float4* x1p = (const float4*)(Xs + 1 * Dn + dh * (Dn / 2));
    const float4* x2p = (const float4*)(Xs + 2 * Dn + dh * (Dn / 2));
    const float4* x3p = (const float4*)(Xs + 3 * Dn + dh * (Dn / 2));
    float a0 = 0.f, a1 = 0.f, a2 = 0.f, a3 = 0.f;
    #pragma unroll 8
    for (int d4 = 0; d4 < 32; ++d4) {
        float4 w  = Wrow[d4];
        float4 x0 = x0p[d4], x1 = x1p[d4], x2 = x2p[d4], x3 = x3p[d4];  // LDS broadcast
        a0 = fmaf(w.x, x0.x, a0); a0 = fmaf(w.y, x0.y, a0);
        a0 = fmaf(w.z, x0.z, a0); a0 = fmaf(w.w, x0.w, a0);
        a1 = fmaf(w.x, x1.x, a1); a1 = fmaf(w.y, x1.y, a1);
        a1 = fmaf(w.z, x1.z, a1); a1 = fmaf(w.w, x1.w, a1);
        a2 = fmaf(w.x, x2.x, a2); a2 = fmaf(w.y, x2.y, a2);
        a2 = fmaf(w.z, x2.z, a2); a2 = fmaf(w.w, x2.w, a2);
        a3 = fmaf(w.x, x3.x, a3); a3 = fmaf(w.y, x3.y, a3);
        a3 = fmaf(w.z, x3.z, a3); a3 = fmaf(w.w, x3.w, a3);
    }
    if (dh) ((float4*)pr)[c] = make_float4(a0, a1, a2, a3);
    __syncthreads();
    if (!dh) {
        float4 p = ((const float4*)pr)[c];
        QK[(r0 + 0) * 128 + c] = __expf(2.0f * (a0 + p.x));
        QK[(r0 + 1) * 128 + c] = __expf(2.0f * (a1 + p.y));
        QK[(r0 + 2) * 128 + c] = __expf(2.0f * (a2 + p.z));
        QK[(r0 + 3) * 128 + c] = __expf(2.0f * (a3 + p.w));
    }
}

// ---------------- Kernel B: scores + softmax + context (IPB=4, 512 thr) ----------------
// grid = ROWS/IPB = 512 blocks, 512 threads (8 waves). Thread = (j = tid&255, kh = tid>>8).
__global__ __launch_bounds__(512, 4) void attn_kernel(
    const float* __restrict__ X,    // (2048,256)
    const float* __restrict__ QK,   // (2048,128) exp'd
    const float* __restrict__ W2,   // (64,)
    float* __restrict__ out)        // (2048,512)
{
    __shared__ float eq_s[IPB * Kn];        // 1 KB
    __shared__ float w2_s[Kn];              // 256 B
    __shared__ float Sp[2 * IPB * Ln];      // [kh][i][j] partial T, 8 KB
    __shared__ float4 S4[Ln];               // final attn per j (components = i), 4 KB
    __shared__ float4 red[8 * IPB * 64];    // [wv][i][dquad], 32 KB
    // total ~45.3 KB -> 2 blocks/CU (grid-limited anyway); 16 waves/CU

    const int tid = threadIdx.x;
    const int b  = blockIdx.x >> 6;             // 64 blocks per batch
    const int i0 = (blockIdx.x & 63) * IPB;
    const int j  = tid & 255;                   // key row owned
    const int kh = tid >> 8;                    // k-half: 0 -> k[0:32), 1 -> k[32:64)

    if (tid < Kn) w2_s[tid] = W2[tid];
    if (tid >= 256) {                           // waves 4-7 load Eq (256 values)
        int t = tid - 256;
        int ii = t >> 6, kk = t & 63;
        eq_s[ii * Kn + kk] = QK[(b * Ln + i0 + ii) * 128 + kk];
    }

    // prefetch this thread's Ek half-row (32 floats) to registers
    float ekr[32];
    {
        const float4* kj4 = (const float4*)(QK + (b * Ln + j) * 128 + 64 + kh * 32);
        #pragma unroll
        for (int q = 0; q < 8; ++q) {
            float4 v = kj4[q];
            ekr[q * 4 + 0] = v.x; ekr[q * 4 + 1] = v.y;
            ekr[q * 4 + 2] = v.z; ekr[q * 4 + 3] = v.w;
        }
    }
    __syncthreads();

    // Phase 1: partial T_i over this thread's 32 k's.
    {
        float s0 = 0.f, s1 = 0.f, s2 = 0.f, s3 = 0.f;
        const float4* w4  = ((const float4*)w2_s) + kh * 8;
        const float4* q4a = ((const float4*)(eq_s          )) + kh * 8;
        const float4* q4b = ((const float4*)(eq_s +     Kn )) + kh * 8;
        const float4* q4c = ((const float4*)(eq_s + 2 * Kn )) + kh * 8;
        const float4* q4d = ((const float4*)(eq_s + 3 * Kn )) + kh * 8;
        #pragma unroll
        for (int k4 = 0; k4 < 8; ++k4) {
            float4 w  = w4[k4];                 // uniform LDS broadcast
            float4 q0 = q4a[k4], q1 = q4b[k4], q2 = q4c[k4], q3 = q4d[k4];
            #pragma unroll
            for (int c = 0; c < 4; ++c) {
                float ek = ekr[k4 * 4 + c];
                float wk = (c == 0) ? w.x : (c == 1) ? w.y : (c == 2) ? w.z : w.w;
                float e0 = (c == 0) ? q0.x : (c == 1) ? q0.y : (c == 2) ? q0.z : q0.w;
                float e1 = (c == 0) ? q1.x : (c == 1) ? q1.y : (c == 2) ? q1.z : q1.w;
                float e2 = (c == 0) ? q2.x : (c == 1) ? q2.y : (c == 2) ? q2.z : q2.w;
                float e3 = (c == 0) ? q3.x : (c == 1) ? q3.y : (c == 2) ? q3.z : q3.w;
                s0 = fmaf(wk, __builtin_amdgcn_rcpf(fmaf(e0, ek, 1.0f)), s0);
                s1 = fmaf(wk, __builtin_amdgcn_rcpf(fmaf(e1, ek, 1.0f)), s1);
                s2 = fmaf(wk, __builtin_amdgcn_rcpf(fmaf(e2, ek, 1.0f)), s2);
                s3 = fmaf(wk, __builtin_amdgcn_rcpf(fmaf(e3, ek, 1.0f)), s3);
            }
        }
        // transposed store [kh][i][j]: lanes stride 4 B -> conflict-free
        Sp[(kh * IPB + 0) * Ln + j] = s0;
        Sp[(kh * IPB + 1) * Ln + j] = s1;
        Sp[(kh * IPB + 2) * Ln + j] = s2;
        Sp[(kh * IPB + 3) * Ln + j] = s3;
    }
    __syncthreads();

    // Phase 2 (waves 0-3): softmax over j of (-2T), row i = wv.
    // Waves 4-7 concurrently: inputs -> out copy (independent of LDS).
    {
        const int wv = tid >> 6, lane = tid & 63;
        if (wv < IPB) {
            const float* p0 = Sp + wv * Ln;             // kh=0 partials, row wv
            const float* p1 = Sp + (IPB + wv) * Ln;     // kh=1 partials
            float T0 = p0[lane      ] + p1[lane      ];
            float T1 = p0[lane +  64] + p1[lane +  64];
            float T2 = p0[lane + 128] + p1[lane + 128];
            float T3 = p0[lane + 192] + p1[lane + 192];
            float e0 = __expf(-2.0f * T0);
            float e1 = __expf(-2.0f * T1);
            float e2 = __expf(-2.0f * T2);
            float e3 = __expf(-2.0f * T3);
            float sum = (e0 + e1) + (e2 + e3);
            #pragma unroll
            for (int off = 32; off > 0; off >>= 1)
                sum += __shfl_xor(sum, off);
            float inv = 1.0f / sum;
            ((float*)S4)[(lane      ) * 4 + wv] = e0 * inv;
            ((float*)S4)[(lane +  64) * 4 + wv] = e1 * inv;
            ((float*)S4)[(lane + 128) * 4 + wv] = e2 * inv;
            ((float*)S4)[(lane + 192) * 4 + wv] = e3 * inv;
        } else {
            int t = tid - 256;
            int ii = t >> 6, q = t & 63;
            const int row = b * Ln + i0 + ii;
            ((float4*)(out + row * 2 * Dn))[q] = ((const float4*)(X + row * Dn))[q];
        }
    }
    __syncthreads();

    // Phase 3: context, j split across 8 waves (32 j each)
    {
        const int wv = tid >> 6, lane = tid & 63;
        float4 acc0 = {0,0,0,0}, acc1 = {0,0,0,0}, acc2 = {0,0,0,0}, acc3 = {0,0,0,0};
        const float4* Xb4 = (const float4*)(X + b * Ln * Dn);
        const int jbase = wv * 32;
        #pragma unroll 8
        for (int jj = 0; jj < 32; ++jj) {
            int jr = jbase + jj;
            float4 at = S4[jr];                // uniform broadcast b128
            float4 x  = Xb4[jr * 64 + lane];   // coalesced 1 KB/wave
            acc0.x = fmaf(at.x, x.x, acc0.x); acc0.y = fmaf(at.x, x.y, acc0.y);
            acc0.z = fmaf(at.x, x.z, acc0.z); acc0.w = fmaf(at.x, x.w, acc0.w);
            acc1.x = fmaf(at.y, x.x, acc1.x); acc1.y = fmaf(at.y, x.y, acc1.y);
            acc1.z = fmaf(at.y, x.z, acc1.z); acc1.w = fmaf(at.y, x.w, acc1.w);
            acc2.x = fmaf(at.z, x.x, acc2.x); acc2.y = fmaf(at.z, x.y, acc2.y);
            acc2.z = fmaf(at.z, x.z, acc2.z); acc2.w = fmaf(at.z, x.w, acc2.w);
            acc3.x = fmaf(at.w, x.x, acc3.x); acc3.y = fmaf(at.w, x.y, acc3.y);
            acc3.z = fmaf(at.w, x.z, acc3.z); acc3.w = fmaf(at.w, x.w, acc3.w);
        }
        red[(wv * IPB + 0) * 64 + lane] = acc0;
        red[(wv * IPB + 1) * 64 + lane] = acc1;
        red[(wv * IPB + 2) * 64 + lane] = acc2;
        red[(wv * IPB + 3) * 64 + lane] = acc3;
    }
    __syncthreads();

    // Epilogue (waves 0-3): cross-wave reduce of 8 partials + context store
    if (tid < 256) {
        const int i = tid >> 6, q = tid & 63;
        float4 c = {0, 0, 0, 0};
        #pragma unroll
        for (int w = 0; w < 8; ++w) {
            float4 p = red[(w * IPB + i) * 64 + q];
            c.x += p.x; c.y += p.y; c.z += p.z; c.w += p.w;
        }
        const int row = b * Ln + i0 + i;
        ((float4*)(out + row * 2 * Dn + Dn))[q] = c;   // context half
    }
}

extern "C" void kernel_launch(void* const* d_in, const int* in_sizes, int n_in,
                              void* d_out, int out_size, void* d_ws, size_t ws_size,
                              hipStream_t stream) {
    const float* X  = (const float*)d_in[0];   // (8,256,256)
    const float* W1 = (const float*)d_in[1];   // (64,512)
    const float* W2 = (const float*)d_in[2];   // (1,64)
    float* out = (float*)d_out;                // (8,256,512)
    float* QK  = (float*)d_ws;                 // (2048,128) = 1 MB scratch

    proj_kernel<<<ROWS / 4, 256, 0, stream>>>(X, W1, QK);
    attn_kernel<<<ROWS / IPB, 512, 0, stream>>>(X, QK, W2, out);
}